// Round 1
// baseline (268.591 us; speedup 1.0000x reference)
//
#include <hip/hip_runtime.h>
#include <math.h>

typedef unsigned short u16;
typedef __attribute__((ext_vector_type(8))) short frag8;   // 8 x bf16 (4 VGPR)
typedef __attribute__((ext_vector_type(4))) float facc4;   // MFMA accumulator

__device__ __forceinline__ u16 f2bf(float f) {
  union { float f; unsigned u; } v; v.f = f;
  unsigned r = v.u + 0x7FFFu + ((v.u >> 16) & 1u);   // RNE
  return (u16)(r >> 16);
}

__device__ __forceinline__ facc4 mfma16(frag8 a, frag8 b, facc4 c) {
  return __builtin_amdgcn_mfma_f32_16x16x32_bf16(a, b, c, 0, 0, 0);
}

// ---------------- fp32 -> bf16 convert ----------------
__global__ __launch_bounds__(256) void k_cvt(const float* __restrict__ in,
                                             u16* __restrict__ out, int n) {
  int i = (blockIdx.x * 256 + threadIdx.x) * 8;
  if (i >= n) return;
  float4 a = *(const float4*)(in + i);
  float4 b = *(const float4*)(in + i + 4);
  frag8 o;
  o[0] = (short)f2bf(a.x); o[1] = (short)f2bf(a.y);
  o[2] = (short)f2bf(a.z); o[3] = (short)f2bf(a.w);
  o[4] = (short)f2bf(b.x); o[5] = (short)f2bf(b.y);
  o[6] = (short)f2bf(b.z); o[7] = (short)f2bf(b.w);
  *(frag8*)(out + i) = o;
}

// ---------------- xa = x @ lora_a^T  (fp32, [4096][8]) ----------------
__global__ __launch_bounds__(256) void k_xa(const float* __restrict__ x,
                                            const float* __restrict__ la,
                                            float* __restrict__ xa) {
  const int row = blockIdx.x * 4 + (threadIdx.x >> 6);
  const int lane = threadIdx.x & 63;
  const float* xr = x + (size_t)row * 1024;
  float s[8];
#pragma unroll
  for (int j = 0; j < 8; ++j) s[j] = 0.f;
  for (int c = lane * 4; c < 1024; c += 256) {
    float4 xv = *(const float4*)(xr + c);
#pragma unroll
    for (int j = 0; j < 8; ++j) {
      float4 av = *(const float4*)(la + j * 1024 + c);
      s[j] += xv.x * av.x + xv.y * av.y + xv.z * av.z + xv.w * av.w;
    }
  }
#pragma unroll
  for (int j = 0; j < 8; ++j) {
#pragma unroll
    for (int m_ = 1; m_ < 64; m_ <<= 1) s[j] += __shfl_xor(s[j], m_);
  }
  if (lane == 0) {
#pragma unroll
    for (int j = 0; j < 8; ++j) xa[(size_t)row * 8 + j] = s[j];
  }
}

// ---------------- QKV GEMM: [4096,1024]x[3072,1024]^T + bias + LoRA ----------------
// Writes q (scaled by 0.125), k as [B,H,S,D] bf16; v as [B,H,S,D] bf16 (pre-transpose).
__global__ __launch_bounds__(256) void k_gemm_qkv(
    const u16* __restrict__ A, const u16* __restrict__ B,
    const float* __restrict__ bias, const float* __restrict__ xa,
    const float* __restrict__ lb,
    u16* __restrict__ qw, u16* __restrict__ kw, u16* __restrict__ vw) {
  __shared__ __align__(16) u16 As[128 * 64];
  __shared__ __align__(16) u16 Bs[128 * 64];
  const int mbase = blockIdx.y * 128;
  const int nbase = blockIdx.x * 128;
  const int t = threadIdx.x;
  const int lane = t & 63;
  const int w = t >> 6;
  const int wm = w >> 1, wn = w & 1;
  const facc4 vzero = {0.f, 0.f, 0.f, 0.f};
  facc4 acc[4][4];
#pragma unroll
  for (int i = 0; i < 4; ++i)
#pragma unroll
    for (int j = 0; j < 4; ++j) acc[i][j] = vzero;

  for (int kt = 0; kt < 16; ++kt) {
    __syncthreads();
#pragma unroll
    for (int i = 0; i < 4; ++i) {
      int c = t + i * 256;
      int row = c >> 3, cs = c & 7;
      int boff = row * 128 + ((cs * 16) ^ ((row & 7) << 4));
      frag8 da = *(const frag8*)(A + (size_t)(mbase + row) * 1024 + kt * 64 + cs * 8);
      *(frag8*)((char*)As + boff) = da;
      frag8 db = *(const frag8*)(B + (size_t)(nbase + row) * 1024 + kt * 64 + cs * 8);
      *(frag8*)((char*)Bs + boff) = db;
    }
    __syncthreads();
#pragma unroll
    for (int ks = 0; ks < 2; ++ks) {
      frag8 af[4], bfr[4];
#pragma unroll
      for (int mi = 0; mi < 4; ++mi) {
        int row = wm * 64 + mi * 16 + (lane & 15);
        int off = (ks * 64 + ((lane >> 4) << 4)) ^ ((row & 7) << 4);
        af[mi] = *(const frag8*)((const char*)As + row * 128 + off);
      }
#pragma unroll
      for (int ni = 0; ni < 4; ++ni) {
        int row = wn * 64 + ni * 16 + (lane & 15);
        int off = (ks * 64 + ((lane >> 4) << 4)) ^ ((row & 7) << 4);
        bfr[ni] = *(const frag8*)((const char*)Bs + row * 128 + off);
      }
#pragma unroll
      for (int mi = 0; mi < 4; ++mi)
#pragma unroll
        for (int ni = 0; ni < 4; ++ni)
          acc[mi][ni] = mfma16(af[mi], bfr[ni], acc[mi][ni]);
    }
  }
  // epilogue: bias + LoRA(fp32) + split/scale/scatter
  const int which = nbase >> 10;   // block-uniform: 0=q 1=k 2=v
  const int r0 = (lane >> 4) << 2;
#pragma unroll
  for (int ni = 0; ni < 4; ++ni) {
    const int gc = nbase + wn * 64 + ni * 16 + (lane & 15);
    const float bi = bias[gc];
    const float4 lb0 = *(const float4*)(lb + (size_t)gc * 8);
    const float4 lb1 = *(const float4*)(lb + (size_t)gc * 8 + 4);
    const int e = gc & 1023, h = e >> 6, d = e & 63;
#pragma unroll
    for (int mi = 0; mi < 4; ++mi) {
#pragma unroll
      for (int r = 0; r < 4; ++r) {
        const int gr = mbase + wm * 64 + mi * 16 + r0 + r;
        const float4 xa0 = *(const float4*)(xa + (size_t)gr * 8);
        const float4 xa1 = *(const float4*)(xa + (size_t)gr * 8 + 4);
        float v = acc[mi][ni][r] + bi
                + xa0.x * lb0.x + xa0.y * lb0.y + xa0.z * lb0.z + xa0.w * lb0.w
                + xa1.x * lb1.x + xa1.y * lb1.y + xa1.z * lb1.z + xa1.w * lb1.w;
        const int bb = gr >> 11, s = gr & 2047;
        const size_t idx = ((size_t)(bb * 16 + h) * 2048 + (size_t)s) * 64 + d;
        if (which == 0)      qw[idx] = f2bf(v * 0.125f);
        else if (which == 1) kw[idx] = f2bf(v);
        else                 vw[idx] = f2bf(v);
      }
    }
  }
}

// ---------------- V transpose: [B,H,S,D] -> [B,H,D,S] ----------------
__global__ __launch_bounds__(256) void k_vt(const u16* __restrict__ vp,
                                            u16* __restrict__ vt) {
  __shared__ u16 tile[64][72];
  const int s0 = blockIdx.x * 64;
  const size_t hoff = (size_t)blockIdx.y * (2048 * 64);
  const int t = threadIdx.x;
#pragma unroll
  for (int i = 0; i < 2; ++i) {
    int c = t + i * 256;
    int r = c >> 3, c8 = (c & 7) * 8;
    frag8 d = *(const frag8*)(vp + hoff + (size_t)(s0 + r) * 64 + c8);
#pragma unroll
    for (int j = 0; j < 8; ++j) tile[r][c8 + j] = (u16)d[j];
  }
  __syncthreads();
#pragma unroll
  for (int i = 0; i < 2; ++i) {
    int c = t + i * 256;
    int dd = c >> 3, scol = (c & 7) * 8;
    frag8 o;
#pragma unroll
    for (int j = 0; j < 8; ++j) o[j] = (short)tile[scol + j][dd];
    *(frag8*)(vt + hoff + (size_t)dd * 2048 + s0 + scol) = o;
  }
}

// ---------------- flash attention ----------------
// q,k: [B,H,S,D] bf16 (q pre-scaled); vt: [B,H,D,S] bf16; mask [B,S,S] f32
// out: [B,S,H*D] bf16
__global__ __launch_bounds__(256) void k_attn(
    const u16* __restrict__ qw, const u16* __restrict__ kw,
    const u16* __restrict__ vt, const float* __restrict__ mask,
    u16* __restrict__ ao_out) {
  __shared__ __align__(16) u16 Ks[64 * 64];
  __shared__ __align__(16) u16 Vs[64 * 64];   // [d][kv], swizzled
  __shared__ __align__(16) u16 Ps[4][16 * 64];
  const int qt = blockIdx.x, bh = blockIdx.y;
  const int b = bh >> 4, h = bh & 15;
  const int t = threadIdx.x, lane = t & 63, w = t >> 6;
  const int qbase = qt * 64;
  const size_t hoff = (size_t)bh * (2048 * 64);
  const int l15 = lane & 15, lg = lane >> 4;
  const int r0 = lg << 2;
  frag8 qf[2];
  {
    const u16* qp = qw + hoff + (size_t)(qbase + w * 16 + l15) * 64 + (lg << 3);
    qf[0] = *(const frag8*)qp;
    qf[1] = *(const frag8*)(qp + 32);
  }
  const facc4 vzero = {0.f, 0.f, 0.f, 0.f};
  float mrun[4], lrun[4];
  facc4 oacc[4];
#pragma unroll
  for (int r = 0; r < 4; ++r) { mrun[r] = -__builtin_inff(); lrun[r] = 0.f; }
#pragma unroll
  for (int nb = 0; nb < 4; ++nb) oacc[nb] = vzero;
  const float L2E = 1.44269504088896341f;

  for (int kv0 = 0; kv0 < 2048; kv0 += 64) {
    __syncthreads();
#pragma unroll
    for (int i = 0; i < 2; ++i) {
      int c = t + i * 256;
      int row = c >> 3, cs = c & 7;
      int boff = row * 128 + ((cs * 16) ^ ((row & 7) << 4));
      frag8 dk = *(const frag8*)(kw + hoff + (size_t)(kv0 + row) * 64 + cs * 8);
      *(frag8*)((char*)Ks + boff) = dk;
      frag8 dv = *(const frag8*)(vt + hoff + (size_t)row * 2048 + kv0 + cs * 8);
      *(frag8*)((char*)Vs + boff) = dv;
    }
    __syncthreads();
    // S = Q K^T (+mask)
    facc4 S[4];
#pragma unroll
    for (int nb = 0; nb < 4; ++nb) {
      int row = nb * 16 + l15;
      int sw = (row & 7) << 4;
      frag8 b0 = *(const frag8*)((const char*)Ks + row * 128 + ((lg << 4) ^ sw));
      frag8 b1 = *(const frag8*)((const char*)Ks + row * 128 + ((64 + (lg << 4)) ^ sw));
      facc4 z = vzero;
      z = mfma16(qf[0], b0, z);
      z = mfma16(qf[1], b1, z);
      S[nb] = z;
    }
#pragma unroll
    for (int r = 0; r < 4; ++r) {
      const float* mr = mask + ((size_t)(b * 2048 + qbase + w * 16 + r0 + r)) * 2048 + kv0;
#pragma unroll
      for (int nb = 0; nb < 4; ++nb) S[nb][r] += mr[nb * 16 + l15];
    }
    // online softmax
    float tm[4];
#pragma unroll
    for (int r = 0; r < 4; ++r)
      tm[r] = fmaxf(fmaxf(S[0][r], S[1][r]), fmaxf(S[2][r], S[3][r]));
#pragma unroll
    for (int m_ = 1; m_ < 16; m_ <<= 1)
#pragma unroll
      for (int r = 0; r < 4; ++r) tm[r] = fmaxf(tm[r], __shfl_xor(tm[r], m_));
    float sc[4];
#pragma unroll
    for (int r = 0; r < 4; ++r) {
      float nm = fmaxf(mrun[r], tm[r]);
      sc[r] = exp2f((mrun[r] - nm) * L2E);
      mrun[r] = nm;
    }
    float ps[4] = {0.f, 0.f, 0.f, 0.f};
    u16 pb[4][4];
#pragma unroll
    for (int nb = 0; nb < 4; ++nb)
#pragma unroll
      for (int r = 0; r < 4; ++r) {
        float p = exp2f((S[nb][r] - mrun[r]) * L2E);
        ps[r] += p;
        pb[nb][r] = f2bf(p);
      }
#pragma unroll
    for (int m_ = 1; m_ < 16; m_ <<= 1)
#pragma unroll
      for (int r = 0; r < 4; ++r) ps[r] += __shfl_xor(ps[r], m_);
    facc4 scv = {sc[0], sc[1], sc[2], sc[3]};
#pragma unroll
    for (int r = 0; r < 4; ++r) lrun[r] = lrun[r] * sc[r] + ps[r];
#pragma unroll
    for (int nb = 0; nb < 4; ++nb) oacc[nb] *= scv;
    // P -> LDS (swizzled), wave-private
    u16* pw = Ps[w];
#pragma unroll
    for (int r = 0; r < 4; ++r) {
      int row = r0 + r;
      int sw = (row & 7) << 4;
#pragma unroll
      for (int nb = 0; nb < 4; ++nb) {
        int boff = row * 128 + (((nb * 16 + l15) * 2) ^ sw);
        *(u16*)((char*)pw + boff) = pb[nb][r];
      }
    }
    // O += P V
    int swp = (l15 & 7) << 4;
#pragma unroll
    for (int ks = 0; ks < 2; ++ks) {
      frag8 pa = *(const frag8*)((const char*)pw + l15 * 128 + ((ks * 64 + (lg << 4)) ^ swp));
#pragma unroll
      for (int nb = 0; nb < 4; ++nb) {
        int row = nb * 16 + l15;
        int sw = (row & 7) << 4;
        frag8 vb = *(const frag8*)((const char*)Vs + row * 128 + ((ks * 64 + (lg << 4)) ^ sw));
        oacc[nb] = mfma16(pa, vb, oacc[nb]);
      }
    }
  }
  // epilogue: normalize + store [B,S,E] bf16
#pragma unroll
  for (int r = 0; r < 4; ++r) {
    float inv = 1.0f / lrun[r];
    size_t rowoff = ((size_t)(b * 2048 + qbase + w * 16 + r0 + r)) * 1024 + h * 64;
#pragma unroll
    for (int nb = 0; nb < 4; ++nb)
      ao_out[rowoff + nb * 16 + l15] = f2bf(oacc[nb][r] * inv);
  }
}

// ---------------- out proj GEMM: [4096,1024]x[1024,1024]^T + bias -> fp32 ----------------
__global__ __launch_bounds__(256) void k_gemm_out(
    const u16* __restrict__ A, const u16* __restrict__ B,
    const float* __restrict__ bias, float* __restrict__ out) {
  __shared__ __align__(16) u16 As[128 * 64];
  __shared__ __align__(16) u16 Bs[128 * 64];
  const int mbase = blockIdx.y * 128;
  const int nbase = blockIdx.x * 128;
  const int t = threadIdx.x;
  const int lane = t & 63;
  const int w = t >> 6;
  const int wm = w >> 1, wn = w & 1;
  const facc4 vzero = {0.f, 0.f, 0.f, 0.f};
  facc4 acc[4][4];
#pragma unroll
  for (int i = 0; i < 4; ++i)
#pragma unroll
    for (int j = 0; j < 4; ++j) acc[i][j] = vzero;

  for (int kt = 0; kt < 16; ++kt) {
    __syncthreads();
#pragma unroll
    for (int i = 0; i < 4; ++i) {
      int c = t + i * 256;
      int row = c >> 3, cs = c & 7;
      int boff = row * 128 + ((cs * 16) ^ ((row & 7) << 4));
      frag8 da = *(const frag8*)(A + (size_t)(mbase + row) * 1024 + kt * 64 + cs * 8);
      *(frag8*)((char*)As + boff) = da;
      frag8 db = *(const frag8*)(B + (size_t)(nbase + row) * 1024 + kt * 64 + cs * 8);
      *(frag8*)((char*)Bs + boff) = db;
    }
    __syncthreads();
#pragma unroll
    for (int ks = 0; ks < 2; ++ks) {
      frag8 af[4], bfr[4];
#pragma unroll
      for (int mi = 0; mi < 4; ++mi) {
        int row = wm * 64 + mi * 16 + (lane & 15);
        int off = (ks * 64 + ((lane >> 4) << 4)) ^ ((row & 7) << 4);
        af[mi] = *(const frag8*)((const char*)As + row * 128 + off);
      }
#pragma unroll
      for (int ni = 0; ni < 4; ++ni) {
        int row = wn * 64 + ni * 16 + (lane & 15);
        int off = (ks * 64 + ((lane >> 4) << 4)) ^ ((row & 7) << 4);
        bfr[ni] = *(const frag8*)((const char*)Bs + row * 128 + off);
      }
#pragma unroll
      for (int mi = 0; mi < 4; ++mi)
#pragma unroll
        for (int ni = 0; ni < 4; ++ni)
          acc[mi][ni] = mfma16(af[mi], bfr[ni], acc[mi][ni]);
    }
  }
  const int r0 = (lane >> 4) << 2;
#pragma unroll
  for (int ni = 0; ni < 4; ++ni) {
    const int gc = nbase + wn * 64 + ni * 16 + (lane & 15);
    const float bi = bias[gc];
#pragma unroll
    for (int mi = 0; mi < 4; ++mi)
#pragma unroll
      for (int r = 0; r < 4; ++r) {
        const int gr = mbase + wm * 64 + mi * 16 + r0 + r;
        out[(size_t)gr * 1024 + gc] = acc[mi][ni][r] + bi;
      }
  }
}

extern "C" void kernel_launch(void* const* d_in, const int* in_sizes, int n_in,
                              void* d_out, int out_size, void* d_ws, size_t ws_size,
                              hipStream_t stream) {
  const float* x    = (const float*)d_in[0];
  const float* mask = (const float*)d_in[1];
  const float* wi   = (const float*)d_in[2];
  const float* bi   = (const float*)d_in[3];
  const float* wo   = (const float*)d_in[4];
  const float* bo   = (const float*)d_in[5];
  const float* la   = (const float*)d_in[6];
  const float* lb   = (const float*)d_in[7];
  float* out = (float*)d_out;

  char* ws = (char*)d_ws;
  u16* x_bf  = (u16*)ws;              ws += (size_t)4096 * 1024 * 2;
  u16* w_bf  = (u16*)ws;              ws += (size_t)3072 * 1024 * 2;
  u16* wo_bf = (u16*)ws;              ws += (size_t)1024 * 1024 * 2;
  u16* q_ws  = (u16*)ws;              ws += (size_t)4096 * 1024 * 2;
  u16* k_ws  = (u16*)ws;              ws += (size_t)4096 * 1024 * 2;
  u16* v_pre = (u16*)ws;              ws += (size_t)4096 * 1024 * 2;
  u16* v_t   = (u16*)ws;              ws += (size_t)4096 * 1024 * 2;
  u16* a_ws  = (u16*)ws;              ws += (size_t)4096 * 1024 * 2;
  float* xa  = (float*)ws;            ws += (size_t)4096 * 8 * 4;

  k_cvt<<<dim3(2048), dim3(256), 0, stream>>>(x, x_bf, 4096 * 1024);
  k_cvt<<<dim3(1536), dim3(256), 0, stream>>>(wi, w_bf, 3072 * 1024);
  k_cvt<<<dim3(512),  dim3(256), 0, stream>>>(wo, wo_bf, 1024 * 1024);
  k_xa<<<dim3(1024), dim3(256), 0, stream>>>(x, la, xa);
  k_gemm_qkv<<<dim3(24, 32), dim3(256), 0, stream>>>(x_bf, w_bf, bi, xa, lb,
                                                     q_ws, k_ws, v_pre);
  k_vt<<<dim3(32, 32), dim3(256), 0, stream>>>(v_pre, v_t);
  k_attn<<<dim3(32, 32), dim3(256), 0, stream>>>(q_ws, k_ws, v_t, mask, a_ws);
  k_gemm_out<<<dim3(8, 32), dim3(256), 0, stream>>>(a_ws, wo_bf, bo, out);
}